// Round 4
// baseline (895.994 us; speedup 1.0000x reference)
//
#include <hip/hip_runtime.h>
#include <math.h>

#define NUM_K 4096
#define DIM   256
#define TLEN  1024
#define DT    (DIM * TLEN)     // 262144, per-batch z stride
#define WCAP  1024             // per-wave candidate capacity (E ~320, 3x headroom)

typedef short bf16x8 __attribute__((ext_vector_type(8)));   // 8 bf16 in 4 VGPRs
typedef float f32x4  __attribute__((ext_vector_type(4)));

// float -> bf16, round-to-nearest-even (bit trick; inputs finite)
static __device__ __forceinline__ unsigned short f2bf(float x) {
  unsigned u = __float_as_uint(x);
  u += 0x7fffu + ((u >> 16) & 1u);
  return (unsigned short)(u >> 16);
}

static __device__ __forceinline__ f32x4 mfma16(bf16x8 a, bf16x8 b, f32x4 c) {
  return __builtin_amdgcn_mfma_f32_16x16x32_bf16(a, b, c, 0, 0, 0);
}

// Max-reduce across each DPP row (16 lanes) — 4 in-row permutations cover all 16.
// old=src: any disabled-lane case degrades to identity => reduce over a SUBSET,
// which can only LOWER the running max => looser threshold => still-correct superset.
static __device__ __forceinline__ float dppmax16(float v) {
  int x = __float_as_int(v); int y;
  y = __builtin_amdgcn_update_dpp(x, x, 0xB1, 0xF, 0xF, false);   // quad_perm(1,0,3,2)
  v = fmaxf(v, __int_as_float(y)); x = __float_as_int(v);
  y = __builtin_amdgcn_update_dpp(x, x, 0x4E, 0xF, 0xF, false);   // quad_perm(2,3,0,1)
  v = fmaxf(v, __int_as_float(y)); x = __float_as_int(v);
  y = __builtin_amdgcn_update_dpp(x, x, 0x141, 0xF, 0xF, false);  // row_half_mirror
  v = fmaxf(v, __int_as_float(y)); x = __float_as_int(v);
  y = __builtin_amdgcn_update_dpp(x, x, 0x140, 0xF, 0xF, false);  // row_mirror
  v = fmaxf(v, __int_as_float(y));
  return v;
}

// ---------------- K1a: per-code norms m_c = max(||w_c||, 1e-6), numpy-bitwise ----------------
__global__ __launch_bounds__(256) void wnorm_kernel(const float* __restrict__ w,
                                                    float* __restrict__ wnorms) {
  const int k = blockIdx.x * 256 + threadIdx.x;
  const float* row = w + (size_t)k * DIM;
  float p[2];
#pragma unroll
  for (int blk = 0; blk < 2; ++blk) {
    const float* b = row + blk * 128;
    float r[8];
#pragma unroll
    for (int j = 0; j < 8; ++j) r[j] = __fmul_rn(b[j], b[j]);
    for (int i = 8; i < 128; i += 8) {
#pragma unroll
      for (int j = 0; j < 8; ++j) r[j] = __fadd_rn(r[j], __fmul_rn(b[i + j], b[i + j]));
    }
    p[blk] = __fadd_rn(__fadd_rn(__fadd_rn(r[0], r[1]), __fadd_rn(r[2], r[3])),
                       __fadd_rn(__fadd_rn(r[4], r[5]), __fadd_rn(r[6], r[7])));
  }
  wnorms[k] = fmaxf(__fsqrt_rn(__fadd_rn(p[0], p[1])), 1e-6f);
}

// ---------------- K1b: fp32 normalized codebook wnf32[k][d] = fdiv(w, m_k) ----------------
__global__ __launch_bounds__(256) void wnf32_kernel(const float* __restrict__ w,
                                                    const float* __restrict__ wnorms,
                                                    float* __restrict__ wnf) {
  const int idx = blockIdx.x * 256 + threadIdx.x;   // 0..262143 (float4 units)
  const float m = wnorms[idx >> 6];
  const float4 v = *reinterpret_cast<const float4*>(w + (size_t)idx * 4);
  float4 o;
  o.x = __fdiv_rn(v.x, m); o.y = __fdiv_rn(v.y, m);
  o.z = __fdiv_rn(v.z, m); o.w = __fdiv_rn(v.w, m);
  *reinterpret_cast<float4*>(wnf + (size_t)idx * 4) = o;
}

// ---------------- K1c: bf16 B-fragment image of wn ----------------
// fragid = chunk*32 + kb*4 + jg; each fragment 1 KB = 64 lanes x 16 B:
// B[k = (lane>>4)*8 + u][col = jg*16 + (lane&15)] for mfma 16x16x32 bf16.
__global__ __launch_bounds__(256) void wfrag_kernel(const float* __restrict__ wnf,
                                                    unsigned short* __restrict__ img) {
  const int t = blockIdx.x * 256 + threadIdx.x;
  const int lane = t & 63;
  const int fragid = t >> 6;                           // 0..2047
  const int jg = fragid & 3;
  const int kb = (fragid >> 2) & 7;
  const int chunk = fragid >> 5;
  const int c  = (chunk << 6) + (jg << 4) + (lane & 15);
  const int d0 = (kb << 5) + ((lane >> 4) << 3);
  const float* src = wnf + (size_t)c * DIM + d0;
  union { bf16x8 v; unsigned short u[8]; } o;
#pragma unroll
  for (int u = 0; u < 8; ++u) o.u[u] = f2bf(src[u]);
  *reinterpret_cast<bf16x8*>(img + (size_t)fragid * 512 + lane * 8) = o.v;
}

// ---------------- K2: main fused kernel ----------------
// R4: SINGLE-pass GEMM. Per chunk: MFMA -> per-token running cross-lane max via
// DPP (quad_perm/row_mirror, pure VALU) -> collect scores >= runmax - window into
// per-wave LDS lists. running_max <= final_max, so the collected set is a certified
// SUPERSET of the two-pass candidate set. Verdict: exact numpy fp32 seq-FMA rescore
// of candidates + atomicMax64 on packed key (monotone-float(s)<<32 | (4095-c)) =>
// max exact score, lowest code on ties — bit-identical verdict to prior rounds.
__global__ __launch_bounds__(256, 2) void vq_main_kernel(
    const float* __restrict__ z, const float* __restrict__ weight,
    const unsigned short* __restrict__ wimg, const float* __restrict__ wnf32,
    float* __restrict__ znT, float* __restrict__ out_codes,
    float* __restrict__ counts, float* __restrict__ loss_accum) {
  __shared__ float pp[2][64];
  __shared__ float tnorm[64];
  __shared__ int   fidx[64];
  __shared__ int   clist[4][WCAP];
  __shared__ int   wcnt[4];
  __shared__ unsigned long long tokbest[64];

  const int tid  = threadIdx.x;
  const int bb   = blockIdx.x >> 4;
  const int t0   = (blockIdx.x & 15) << 6;
  const int lane = tid & 63;
  const int wv   = tid >> 6;         // wave 0..3
  const int wr   = wv >> 1;          // token half (32 tokens)
  const int wc   = wv & 1;           // code half within a 64-code chunk
  const float* zb = z + (size_t)bb * DT + t0;

  // ---- per-token norms, numpy-bitwise pairwise scheme; 128 threads (tok, 128-block) ----
  if (tid < 128) {
    const int tok = tid & 63, blk = tid >> 6;
    const float* zc = zb + tok;
    float r[8];
#pragma unroll
    for (int j = 0; j < 8; ++j) {
      const float v = zc[(size_t)(blk * 128 + j) * TLEN];
      r[j] = __fmul_rn(v, v);
    }
    for (int i = 8; i < 128; i += 8) {
#pragma unroll
      for (int j = 0; j < 8; ++j) {
        const float v = zc[(size_t)(blk * 128 + i + j) * TLEN];
        r[j] = __fadd_rn(r[j], __fmul_rn(v, v));
      }
    }
    pp[blk][tok] = __fadd_rn(__fadd_rn(__fadd_rn(r[0], r[1]), __fadd_rn(r[2], r[3])),
                             __fadd_rn(__fadd_rn(r[4], r[5]), __fadd_rn(r[6], r[7])));
  }
  if (tid < 4)  wcnt[tid] = 0;
  if (tid < 64) tokbest[tid] = 0ull;
  __syncthreads();
  if (tid < 64) tnorm[tid] = fmaxf(__fsqrt_rn(__fadd_rn(pp[0][tid], pp[1][tid])), 1e-6f);
  __syncthreads();

  // ---- znT = flat_z_norm (token-major), written BEFORE the GEMM ----
  {
    const int tok = tid & 63, seg = tid >> 6;
    const float m = tnorm[tok];
    const float* zc = zb + tok;
    float* orow = znT + (size_t)((bb << 10) + t0 + tok) * DIM + (seg << 6);
#pragma unroll 4
    for (int k4 = 0; k4 < 16; ++k4) {
      float4 o;
      o.x = __fdiv_rn(zc[(size_t)((seg << 6) + (k4 << 2) + 0) * TLEN], m);
      o.y = __fdiv_rn(zc[(size_t)((seg << 6) + (k4 << 2) + 1) * TLEN], m);
      o.z = __fdiv_rn(zc[(size_t)((seg << 6) + (k4 << 2) + 2) * TLEN], m);
      o.w = __fdiv_rn(zc[(size_t)((seg << 6) + (k4 << 2) + 3) * TLEN], m);
      *reinterpret_cast<float4*>(&orow[k4 << 2]) = o;
    }
  }

  // ---- A-fragments: raw z -> bf16 in registers ----
  bf16x8 afr[2][8];
  {
    const int tloc = (wr << 5) + (lane & 15);
    const int dr   = (lane >> 4) << 3;
#pragma unroll
    for (int i = 0; i < 2; ++i) {
      const float* zc = zb + tloc + (i << 4);
#pragma unroll
      for (int kb = 0; kb < 8; ++kb) {
        union { bf16x8 v; unsigned short u[8]; } a;
#pragma unroll
        for (int u = 0; u < 8; ++u)
          a.u[u] = f2bf(zc[(size_t)((kb << 5) + dr + u) * TLEN]);
        afr[i][kb] = a.v;
      }
    }
  }

  // window = 0.02*m_t per token handled by this lane (8 tokens: i x r)
  float wloc[2][4];
  {
    const int tb = (wr << 5) + ((lane >> 4) << 2);
#pragma unroll
    for (int i = 0; i < 2; ++i)
#pragma unroll
      for (int r = 0; r < 4; ++r) wloc[i][r] = 0.02f * tnorm[tb + (i << 4) + r];
  }

  const unsigned short* bbase = wimg + (wc << 10) + (lane << 3);
  const f32x4 zero4 = {0.f, 0.f, 0.f, 0.f};
  const bool lc0 = (wc == 0) && ((lane & 15) == 0);   // lane carrying code chunk*64+0

#define LOADC(buf, ch) do {                                              \
    const unsigned short* p_ = bbase + ((size_t)(ch) << 14);             \
    _Pragma("unroll")                                                    \
    for (int kb_ = 0; kb_ < 8; ++kb_) {                                  \
      buf[kb_]     = *reinterpret_cast<const bf16x8*>(p_ + (kb_ << 11)); \
      buf[kb_ + 8] = *reinterpret_cast<const bf16x8*>(p_ + (kb_ << 11) + 512); \
    }                                                                    \
    __builtin_amdgcn_sched_barrier(0);                                   \
  } while (0)

#define MFMAC(buf, accv) do {                                            \
    __builtin_amdgcn_s_setprio(1);                                       \
    _Pragma("unroll")                                                    \
    for (int kb_ = 0; kb_ < 8; ++kb_) {                                  \
      accv[0][0] = mfma16(afr[0][kb_], buf[kb_],     accv[0][0]);        \
      accv[1][0] = mfma16(afr[1][kb_], buf[kb_],     accv[1][0]);        \
      accv[0][1] = mfma16(afr[0][kb_], buf[kb_ + 8], accv[0][1]);        \
      accv[1][1] = mfma16(afr[1][kb_], buf[kb_ + 8], accv[1][1]);        \
    }                                                                    \
    __builtin_amdgcn_s_setprio(0);                                       \
  } while (0)

  // running max update + threshold collect (certified superset; see header comment)
#define PROCESS(accv, ch) do {                                           \
    if ((ch) == 0 && lc0) {                                              \
      _Pragma("unroll") for (int i_ = 0; i_ < 2; ++i_)                   \
      _Pragma("unroll") for (int r_ = 0; r_ < 4; ++r_)                   \
        accv[i_][0][r_] = -INFINITY;                                     \
    }                                                                    \
    _Pragma("unroll")                                                    \
    for (int i_ = 0; i_ < 2; ++i_) {                                     \
      _Pragma("unroll")                                                  \
      for (int r_ = 0; r_ < 4; ++r_) {                                   \
        float m_ = fmaxf(accv[i_][0][r_], accv[i_][1][r_]);              \
        m_ = dppmax16(m_);                                               \
        v1loc[i_][r_] = fmaxf(v1loc[i_][r_], m_);                        \
        const float t_ = v1loc[i_][r_] - wloc[i_][r_];                   \
        _Pragma("unroll")                                                \
        for (int j_ = 0; j_ < 2; ++j_) {                                 \
          if (accv[i_][j_][r_] >= t_) {                                  \
            const int c_ = ((ch) << 6) + (wc << 5) + (j_ << 4) + (lane & 15); \
            if (c_ != 0) {                                               \
              const int pos_ = atomicAdd(&wcnt[wv], 1);                  \
              if (pos_ < WCAP)                                           \
                clist[wv][pos_] = (c_ << 6) | ((wr << 5) + (i_ << 4) + ((lane >> 4) << 2) + r_); \
            }                                                            \
          }                                                              \
        }                                                                \
      }                                                                  \
    }                                                                    \
  } while (0)

  // ---- SINGLE PASS: score + streaming windowed collection, double-buffered B ----
  float v1loc[2][4];
#pragma unroll
  for (int i = 0; i < 2; ++i)
#pragma unroll
    for (int r = 0; r < 4; ++r) v1loc[i][r] = -INFINITY;
  {
    bf16x8 bA[16], bB[16];
    LOADC(bA, 0);
#pragma unroll 1
    for (int chunk = 0; chunk < 64; chunk += 2) {
      LOADC(bB, chunk + 1);
      f32x4 acc[2][2];
      acc[0][0] = zero4; acc[0][1] = zero4; acc[1][0] = zero4; acc[1][1] = zero4;
      MFMAC(bA, acc);
      PROCESS(acc, chunk);
      if (chunk + 2 < 64) LOADC(bA, chunk + 2);
      f32x4 ac2[2][2];
      ac2[0][0] = zero4; ac2[0][1] = zero4; ac2[1][0] = zero4; ac2[1][1] = zero4;
      MFMAC(bB, ac2);
      PROCESS(ac2, chunk + 1);
    }
  }
#undef LOADC
#undef MFMAC
#undef PROCESS
  __syncthreads();

  // ---- exact numpy-fp32 seq-FMA rescore + atomicMax64 verdict ----
  // key = monotone_uint(s)<<32 | (4095 - c): max s wins; ties -> lowest code.
#pragma unroll 1
  for (int w = 0; w < 4; ++w) {
    const int n = min(wcnt[w], WCAP);
    for (int e = tid; e < n; e += 256) {
      const int pk = clist[w][e];
      const int tloc = pk & 63;
      const int c = pk >> 6;
      const float* za = znT + (size_t)((bb << 10) + t0 + tloc) * DIM;
      const float* wa = wnf32 + (size_t)c * DIM;
      float s = 0.f;
#pragma unroll 8
      for (int d = 0; d < DIM; ++d)
        s = fmaf(za[d], wa[d], s);
      unsigned uk = __float_as_uint(s);
      uk = (uk & 0x80000000u) ? ~uk : (uk | 0x80000000u);
      const unsigned long long key =
          ((unsigned long long)uk << 32) | (unsigned)(4095 - c);
      atomicMax(&tokbest[tloc], key);
    }
  }
  __syncthreads();

  // ---- decode per-token winner ----
  if (tid < 64) {
    const unsigned long long key = tokbest[tid];
    const int bc = 4095 - (int)(key & 0xFFFull);
    fidx[tid] = bc;
    out_codes[bb * TLEN + t0 + tid] = (float)bc;
    atomicAdd(&counts[bc], 1.0f);
  }
  __syncthreads();

  // ---- loss phase: sum (weight[idx] - raw z)^2 ----
  {
    float lpart = 0.f;
#pragma unroll 4
    for (int r = 0; r < 16; ++r) {
      const int tk = (r << 2) + wv;           // one token per wave per round
      const int code = fidx[tk];
      const float* zc = zb + tk;
      const float4 w4 = *reinterpret_cast<const float4*>(
          weight + (size_t)code * DIM + (lane << 2));   // coalesced row read
      float4 zr4;
      zr4.x = zc[(size_t)((lane << 2) + 0) * TLEN];     // scattered, L2-hot
      zr4.y = zc[(size_t)((lane << 2) + 1) * TLEN];
      zr4.z = zc[(size_t)((lane << 2) + 2) * TLEN];
      zr4.w = zc[(size_t)((lane << 2) + 3) * TLEN];
      const float dx = w4.x - zr4.x, dy = w4.y - zr4.y;
      const float dz = w4.z - zr4.z, dw_ = w4.w - zr4.w;
      lpart = fmaf(dx, dx, lpart); lpart = fmaf(dy, dy, lpart);
      lpart = fmaf(dz, dz, lpart); lpart = fmaf(dw_, dw_, lpart);
    }
#pragma unroll
    for (int off = 32; off; off >>= 1) lpart += __shfl_down(lpart, off, 64);
    if (lane == 0) atomicAdd(loss_accum, lpart);
  }
}

// ---------------- K3: new_cs, n, loss scalar + exclusive scan of counts ----------------
__global__ __launch_bounds__(256) void finalize_cs_kernel(
    const float* __restrict__ counts, const float* __restrict__ ema_cs,
    float* __restrict__ out_ncs, float* __restrict__ ws_n,
    const float* __restrict__ loss_accum, float* __restrict__ out_loss,
    int* __restrict__ offsets) {
  __shared__ float redf[4];
  __shared__ int   redi[4];
  const int tid = threadIdx.x;
  const int lane = tid & 63, wv = tid >> 6;
  const int base = tid << 4;
  int cloc[16]; int csum = 0; float fsum = 0.f;
#pragma unroll
  for (int j = 0; j < 16; ++j) {
    const int k = base + j;
    const float cf = counts[k];
    const float v = (k == 0) ? 0.f : 0.99f * ema_cs[k] + 0.01f * cf;
    out_ncs[k] = v; fsum += v;
    cloc[j] = csum; csum += (int)cf;
  }
  int inc = csum;                    // wave-inclusive scan
#pragma unroll
  for (int off = 1; off < 64; off <<= 1) {
    const int t = __shfl_up(inc, off, 64);
    if (lane >= off) inc += t;
  }
  float fs = fsum;
#pragma unroll
  for (int off = 32; off; off >>= 1) fs += __shfl_down(fs, off, 64);
  if (lane == 63) redi[wv] = inc;
  if (lane == 0)  redf[wv] = fs;
  __syncthreads();
  int wbase = 0;
#pragma unroll
  for (int w = 0; w < 4; ++w) wbase += (w < wv) ? redi[w] : 0;
  const int tbase = wbase + inc - csum;   // exclusive base for this thread
#pragma unroll
  for (int j = 0; j < 16; ++j) offsets[base + j] = tbase + cloc[j];
  if (tid == 0) {
    ws_n[0] = redf[0] + redf[1] + redf[2] + redf[3];
    out_loss[0] = 0.25f * loss_accum[0] / 16777216.0f;
  }
}

// ---------------- K3b: scatter token ids into per-code buckets ----------------
__global__ __launch_bounds__(256) void scatter_kernel(
    const float* __restrict__ codes, const int* __restrict__ offsets,
    int* __restrict__ cursor, int* __restrict__ bucket) {
  const int g = blockIdx.x * 256 + threadIdx.x;
  const int c = (int)codes[g];
  const int pos = atomicAdd(&cursor[c], 1);
  bucket[offsets[c] + pos] = g;
}

// ---------------- K3c: dw[k] = sum of znT rows in bucket k (coalesced, no atomics) ----------------
__global__ __launch_bounds__(256) void dw_kernel(
    const float* __restrict__ znT, const float* __restrict__ counts,
    const int* __restrict__ offsets, const int* __restrict__ bucket,
    float* __restrict__ dw) {
  const int c = blockIdx.x;
  const int cnt = (int)counts[c];
  const int off = offsets[c];
  const int tid = threadIdx.x;
  float acc = 0.f;
  for (int i = 0; i < cnt; ++i) {
    const int g = bucket[off + i];
    acc += znT[(size_t)g * DIM + tid];     // 1 KB coalesced row read
  }
  dw[(size_t)c * DIM + tid] = acc;         // writes every row (overwrites wnf32)
}

// ---------------- K4: new_ema_w (in place over dw) + new_weight ----------------
__global__ __launch_bounds__(256) void finalize_w_kernel(
    const float* __restrict__ ema_w, const float* __restrict__ ncs,
    const float* __restrict__ ws_n, float* __restrict__ new_ema_w,
    float* __restrict__ new_weight) {
  const int wid  = threadIdx.x >> 6;
  const int lane = threadIdx.x & 63;
  const int k    = (blockIdx.x << 2) + wid;
  const float n  = ws_n[0];
  const float cs = (ncs[k] + 1e-5f) / (n + 4096.0f * 1e-5f) * n;
  const float* erow = ema_w + k * DIM;
  float* nrow = new_ema_w + k * DIM;
  float* wrow = new_weight + k * DIM;
  const int d0 = lane << 2;
  float u[4]; float ss = 0.f;
#pragma unroll
  for (int j = 0; j < 4; ++j) {
    const float dwv = nrow[d0 + j];
    const float val = (k == 0) ? 0.f : 0.99f * erow[d0 + j] + 0.01f * dwv;
    nrow[d0 + j] = val;
    const float uu = val / cs;
    u[j] = uu;
    ss = fmaf(uu, uu, ss);
  }
#pragma unroll
  for (int off = 32; off; off >>= 1) ss += __shfl_xor(ss, off, 64);
  const float m = fmaxf(sqrtf(ss), 1e-6f);
#pragma unroll
  for (int j = 0; j < 4; ++j) wrow[d0 + j] = u[j] / m;
}

// ---------------- K5: final quantized = weight[idx], overwrites znT region ----------------
__global__ __launch_bounds__(256) void qwrite_kernel(
    const float* __restrict__ codes, const float* __restrict__ weight,
    float* __restrict__ out_q) {
  const int bb = blockIdx.x >> 4;
  const int t0 = (blockIdx.x & 15) << 6;
  const int ln = threadIdx.x & 63, qv = threadIdx.x >> 6;
  const int code = (int)codes[bb * TLEN + t0 + ln];
  const float* wrow = weight + (size_t)code * DIM;
  float* qb = out_q + (size_t)bb * DT + t0 + ln;
#pragma unroll 4
  for (int dd = 0; dd < 64; ++dd) {
    const int d = (qv << 6) + dd;
    qb[(size_t)d * TLEN] = wrow[d];        // gather L2-hot, store coalesced
  }
}

extern "C" void kernel_launch(void* const* d_in, const int* in_sizes, int n_in,
                              void* d_out, int out_size, void* d_ws, size_t ws_size,
                              hipStream_t stream) {
  const float* z      = (const float*)d_in[0];   // [64,256,1024]
  const float* weight = (const float*)d_in[1];   // [4096,256]
  const float* ema_cs = (const float*)d_in[2];   // [4096]
  const float* ema_w  = (const float*)d_in[3];   // [4096,256]

  float* out = (float*)d_out;
  // output layout (floats): quantized | loss | codes | new_weight | new_cs | new_ema_w
  float* out_q     = out;                    // 16777216 (holds znT until qwrite)
  float* out_loss  = out + 16777216;         // 1
  float* out_codes = out + 16777217;         // 65536
  float* out_nw    = out + 16842753;         // 1048576 (temp: wimg/bucket/offsets/cursor)
  float* out_ncs   = out + 17891329;         // 4096
  float* out_new   = out + 17895425;         // 1048576 (wnf32 -> dw, overwritten in order)

  float* counts     = (float*)d_ws;          // 4096 floats
  float* loss_accum = counts + 4096;         // 1
  float* ws_n       = counts + 4097;         // 1
  float* wnorms     = counts + 4352;         // 4096 floats, 16B-aligned

  // Scratch aliased into dead d_out regions:
  // wimg: 2 MiB bf16 image at out_nw+3 (16B-aligned); dead after vq_main.
  // bucket overlays the dead image; offsets/cursor sit past it.
  // wnf32 = out_new region; dead after vq_main, then overwritten by dw_kernel.
  unsigned short* wimg = (unsigned short*)(out_nw + 3);
  int* bucket  = (int*)(out_nw + 3);         // 65536 ints (aliases dead wimg)
  int* offsets = (int*)(out_nw + 524292);    // 4096 ints
  int* cursor  = (int*)(out_nw + 528388);    // 4096 ints
  float* wnf32 = out_new;

  hipMemsetAsync(d_ws, 0, 4098 * sizeof(float), stream);
  hipMemsetAsync(cursor, 0, 4096 * sizeof(int), stream);

  wnorm_kernel<<<16, 256, 0, stream>>>(weight, wnorms);
  wnf32_kernel<<<1024, 256, 0, stream>>>(weight, wnorms, wnf32);
  wfrag_kernel<<<512, 256, 0, stream>>>(wnf32, wimg);
  vq_main_kernel<<<1024, 256, 0, stream>>>(z, weight, wimg, wnf32, out_q /*znT*/,
                                           out_codes, counts, loss_accum);
  finalize_cs_kernel<<<1, 256, 0, stream>>>(counts, ema_cs, out_ncs, ws_n,
                                            loss_accum, out_loss, offsets);
  scatter_kernel<<<256, 256, 0, stream>>>(out_codes, offsets, cursor, bucket);
  dw_kernel<<<NUM_K, 256, 0, stream>>>(out_q /*znT*/, counts, offsets, bucket, out_new);
  finalize_w_kernel<<<NUM_K / 4, 256, 0, stream>>>(ema_w, out_ncs, ws_n,
                                                   out_new, out_nw);
  qwrite_kernel<<<1024, 256, 0, stream>>>(out_codes, weight, out_q);
}